// Round 2
// baseline (1338.070 us; speedup 1.0000x reference)
//
#include <hip/hip_runtime.h>
#include <hip/hip_bf16.h>

// Problem constants
#define BATCH 4
#define DIMC  64
#define HPD   32
#define NH    8
#define WSZ   16
#define HH    128
#define WW    128
#define BW    256           // BATCH * 64 windows
#define MTOK  256           // WSZ*WSZ
#define IMG   (HH*WW)       // 16384
#define ATTN_ELEMS ((size_t)BW*NH*MTOK*MTOK)   // 134217728
#define OUT_ELEMS  ((size_t)BATCH*DIMC*IMG)    // 4194304

// Workspace float offsets
#define WS_WC    0          // 192 combined 1x3 weights (8 out x 8 in x 3)
#define WS_B2    192        // 8 biases
#define WS_PW    256        // 4096: pw weights TRANSPOSED [c][o]
#define WS_REFL  65536      // 4194304 fp32 reflashed
#define WS_DWOUT (65536 + 4194304)
#define WS_RES   (65536 + 2*4194304)

// ---------------- k0: combine ReflashAttn weights + transpose pw ------------
__global__ void prep_kernel(const float* __restrict__ ra_w1,
                            const float* __restrict__ ra_w2,
                            const float* __restrict__ ra_b2,
                            const float* __restrict__ pw_w,
                            float* __restrict__ ws) {
  const int total = 192 + 8 + 4096;
  for (int i = blockIdx.x * blockDim.x + threadIdx.x; i < total;
       i += gridDim.x * blockDim.x) {
    if (i < 192) {
      // Wc[o][j][k] = sum_i w2[o][i] * w1[i][j][0][k]
      int o = i / 24, r = i % 24, j = r / 3, k = r % 3;
      float acc = 0.f;
      #pragma unroll
      for (int t = 0; t < 8; ++t)
        acc += ra_w2[o * 8 + t] * ra_w1[(t * 8 + j) * 3 + k];
      ws[WS_WC + i] = acc;
    } else if (i < 200) {
      ws[WS_B2 + (i - 192)] = ra_b2[i - 192];
    } else {
      int q = i - 200;            // q = o*64 + c in source layout
      int o = q >> 6, c = q & 63;
      ws[WS_PW + c * 64 + o] = pw_w[q];   // store transposed [c][o]
    }
  }
}

// ---------------- k1: fused 1x3 conv + relu + softmax -> attn (fp32) --------
__global__ __launch_bounds__(256) void attn_kernel(
    const float* __restrict__ ra, const float* __restrict__ ws,
    float* __restrict__ attn_out) {
  __shared__ float A[8][258];   // halo-padded input rows (all 8 in-heads)
  __shared__ float wc[200];     // 192 weights + 8 biases
  const int m = blockIdx.x;
  const int bw = blockIdx.y;
  const int t = threadIdx.x;

  const float* base = ra + (size_t)bw * 8 * 65536 + (size_t)m * 256;
  #pragma unroll
  for (int j = 0; j < 8; ++j)
    A[j][t + 1] = base[(size_t)j * 65536 + t];
  if (t < 8) { A[t][0] = 0.f; A[t][257] = 0.f; }
  if (t < 200) wc[t] = ws[t];
  __syncthreads();

  const int lane = t & 63;
  const int wave = t >> 6;
  const int o0 = wave * 2, o1 = o0 + 1;
  float acc0[4], acc1[4];
  const float b0 = wc[192 + o0], b1 = wc[192 + o1];
  #pragma unroll
  for (int q = 0; q < 4; ++q) { acc0[q] = b0; acc1[q] = b1; }

  #pragma unroll
  for (int j = 0; j < 8; ++j) {
    const float w00 = wc[(o0 * 8 + j) * 3 + 0];
    const float w01 = wc[(o0 * 8 + j) * 3 + 1];
    const float w02 = wc[(o0 * 8 + j) * 3 + 2];
    const float w10 = wc[(o1 * 8 + j) * 3 + 0];
    const float w11 = wc[(o1 * 8 + j) * 3 + 1];
    const float w12 = wc[(o1 * 8 + j) * 3 + 2];
    #pragma unroll
    for (int q = 0; q < 4; ++q) {
      const int n = lane + 64 * q;          // halo shift: A index n = logical n-1
      const float a0 = A[j][n], a1 = A[j][n + 1], a2 = A[j][n + 2];
      acc0[q] += w00 * a0 + w01 * a1 + w02 * a2;
      acc1[q] += w10 * a0 + w11 * a1 + w12 * a2;
    }
  }

  #pragma unroll
  for (int q = 0; q < 4; ++q) { acc0[q] = fmaxf(acc0[q], 0.f); acc1[q] = fmaxf(acc1[q], 0.f); }

  float* accs[2] = {acc0, acc1};
  const int os[2] = {o0, o1};
  #pragma unroll
  for (int hh = 0; hh < 2; ++hh) {
    float* a = accs[hh];
    float mx = fmaxf(fmaxf(a[0], a[1]), fmaxf(a[2], a[3]));
    #pragma unroll
    for (int s = 1; s < 64; s <<= 1) mx = fmaxf(mx, __shfl_xor(mx, s, 64));
    float e[4], sum = 0.f;
    #pragma unroll
    for (int q = 0; q < 4; ++q) { e[q] = __expf(a[q] - mx); sum += e[q]; }
    #pragma unroll
    for (int s = 1; s < 64; s <<= 1) sum += __shfl_xor(sum, s, 64);
    const float r = 1.f / sum;
    float* ob = attn_out + ((size_t)(bw * 8 + os[hh]) * 256 + m) * 256;
    #pragma unroll
    for (int q = 0; q < 4; ++q) ob[lane + 64 * q] = e[q] * r;
  }
}

// ---------------- k2: windowed attention apply -> reflashed (fp32 ws) -------
__global__ __launch_bounds__(256) void apply_kernel(
    const float* __restrict__ attn, const float* __restrict__ lms,
    float* __restrict__ refl) {
  __shared__ __align__(16) float xs[256][8];  // [m][d]
  const int bw = blockIdx.x, h = blockIdx.y;
  const int b = bw >> 6, wi = bw & 63, i1 = wi >> 3, i2 = wi & 7;
  const int t = threadIdx.x;

  {
    const int hh = t >> 4, wp = t & 15;
    const int yy = hh * 8 + i1, xx = wp * 8 + i2;   // dilated window partition
    #pragma unroll
    for (int d = 0; d < 8; ++d) {
      const int c = h * 8 + d;
      xs[t][d] = lms[(((size_t)b * 64 + c) * 128 + yy) * 128 + xx];
    }
  }
  __syncthreads();

  float acc[8] = {0, 0, 0, 0, 0, 0, 0, 0};
  const float* ab = attn + ((size_t)bw * 8 + h) * 65536 + t;
  #pragma unroll 4
  for (int mm = 0; mm < 256; ++mm) {
    const float av = ab[(size_t)mm << 8];
    const float4* xp = (const float4*)&xs[mm][0];
    const float4 x0 = xp[0], x1 = xp[1];
    acc[0] += av * x0.x; acc[1] += av * x0.y;
    acc[2] += av * x0.z; acc[3] += av * x0.w;
    acc[4] += av * x1.x; acc[5] += av * x1.y;
    acc[6] += av * x1.z; acc[7] += av * x1.w;
  }

  const int hh = t >> 4, wp = t & 15;
  const int yy = hh * 8 + i1, xx = wp * 8 + i2;
  #pragma unroll
  for (int d = 0; d < 8; ++d) {
    const int c = h * 8 + d;
    refl[(((size_t)b * 64 + c) * 128 + yy) * 128 + xx] = acc[d];
  }
}

// ---------------- k3a: depthwise 3x3 + relu -> dwout ------------------------
__global__ __launch_bounds__(256) void dw_kernel(
    const float* __restrict__ refl, const float* __restrict__ dw_w,
    const float* __restrict__ dw_b, float* __restrict__ dwout) {
  const int idx = blockIdx.x * 256 + threadIdx.x;
  const int x = idx & 127, y = (idx >> 7) & 127;
  const int c = (idx >> 14) & 63, b = idx >> 20;
  const float* in = refl + ((size_t)(b * 64 + c) << 14);
  float w[9];
  #pragma unroll
  for (int k = 0; k < 9; ++k) w[k] = dw_w[c * 9 + k];
  float acc = dw_b[c];
  #pragma unroll
  for (int dy = 0; dy < 3; ++dy) {
    const int yy = y + dy - 1;
    if (yy < 0 || yy > 127) continue;
    #pragma unroll
    for (int dx = 0; dx < 3; ++dx) {
      const int xx = x + dx - 1;
      if (xx < 0 || xx > 127) continue;
      acc += w[dy * 3 + dx] * in[yy * 128 + xx];
    }
  }
  dwout[idx] = fmaxf(acc, 0.f);
}

// ---------------- k3b: 1x1 conv + bias + residual -> res --------------------
__global__ __launch_bounds__(256) void pw_kernel(const float* __restrict__ ws,
                                                 const float* __restrict__ pwb,
                                                 float* __restrict__ res_out) {
  __shared__ __align__(16) float ds[64][64];   // [c][p]
  __shared__ __align__(16) float wsm[64][64];  // [c][o] (already transposed in ws)
  const int tile = blockIdx.x, b = blockIdx.y;
  const int t = threadIdx.x;
  const float* dwout = ws + WS_DWOUT;
  const float* refl = ws + WS_REFL;
  const float* pwT = ws + WS_PW;

  for (int i = t; i < 4096; i += 256) ((float*)wsm)[i] = pwT[i];
  for (int i = t; i < 4096; i += 256) {
    const int c = i >> 6, p = i & 63;
    ds[c][p] = dwout[((size_t)(b * 64 + c) << 14) + tile * 64 + p];
  }
  __syncthreads();

  const int p = t & 63, qo = t >> 6;
  float acc[16];
  #pragma unroll
  for (int i = 0; i < 16; ++i) acc[i] = 0.f;
  for (int c = 0; c < 64; ++c) {
    const float v = ds[c][p];
    const float4* wrow = (const float4*)&wsm[c][0];
    #pragma unroll
    for (int i4 = 0; i4 < 4; ++i4) {
      const float4 w4 = wrow[qo * 4 + i4];
      acc[i4 * 4 + 0] += w4.x * v;
      acc[i4 * 4 + 1] += w4.y * v;
      acc[i4 * 4 + 2] += w4.z * v;
      acc[i4 * 4 + 3] += w4.w * v;
    }
  }
  #pragma unroll
  for (int i = 0; i < 16; ++i) {
    const int o = qo * 16 + i;
    const size_t idx = ((size_t)(b * 64 + o) << 14) + tile * 64 + p;
    res_out[idx] = acc[i] + pwb[o] + refl[idx];
  }
}

// ---------------- k4: fuse 3x3 conv (96->64) + gate -> out (fp32) ----------
__global__ __launch_bounds__(256) void fuse_kernel(
    const float* __restrict__ ws, const float* __restrict__ hp,
    const float* __restrict__ fw, const float* __restrict__ fb,
    float* __restrict__ outp) {
  __shared__ float tile_s[2][324];  // 18x18 halo tile, double buffered
  const int tile = blockIdx.x;      // 64 tiles of 16x16
  const int ocg = blockIdx.y;       // 4 groups of 16 out channels
  const int b = blockIdx.z;
  const int t = threadIdx.x;
  const int ty0 = (tile >> 3) * 16, tx0 = (tile & 7) * 16;
  const int py = t >> 4, px = t & 15;
  const int y = ty0 + py, x = tx0 + px;
  const float* res = ws + WS_RES;
  const float* refl = ws + WS_REFL;

  float acc[16];
  #pragma unroll
  for (int i = 0; i < 16; ++i) acc[i] = 0.f;

  auto load_tile = [&](int ic, int buf) {
    for (int i = t; i < 324; i += 256) {
      const int r = i / 18, cc = i % 18;
      const int gy = ty0 + r - 1, gx = tx0 + cc - 1;
      float v = 0.f;
      if (gy >= 0 && gy < 128 && gx >= 0 && gx < 128) {
        if (ic < 64)
          v = res[(((size_t)b * 64 + ic) * 128 + gy) * 128 + gx];
        else
          v = hp[(((size_t)b * 32 + (ic - 64)) * 128 + gy) * 128 + gx];
      }
      tile_s[buf][i] = v;
    }
  };

  load_tile(0, 0);
  int buf = 0;
  for (int ic = 0; ic < 96; ++ic) {
    __syncthreads();
    if (ic + 1 < 96) load_tile(ic + 1, buf ^ 1);
    float v[9];
    #pragma unroll
    for (int dy = 0; dy < 3; ++dy)
      #pragma unroll
      for (int dx = 0; dx < 3; ++dx)
        v[dy * 3 + dx] = tile_s[buf][(py + dy) * 18 + (px + dx)];
    #pragma unroll
    for (int i = 0; i < 16; ++i) {
      const float* wp = fw + ((size_t)(ocg * 16 + i) * 96 + ic) * 9;
      #pragma unroll
      for (int k = 0; k < 9; ++k) acc[i] += wp[k] * v[k];
    }
    buf ^= 1;
  }

  #pragma unroll
  for (int i = 0; i < 16; ++i) {
    const int o = ocg * 16 + i;
    const size_t idx = (((size_t)b * 64 + o) * 128 + y) * 128 + x;
    outp[idx] = refl[idx] * (acc[i] + fb[o]);
  }
}

extern "C" void kernel_launch(void* const* d_in, const int* in_sizes, int n_in,
                              void* d_out, int out_size, void* d_ws, size_t ws_size,
                              hipStream_t stream) {
  const float* reused = (const float*)d_in[0];
  const float* lms    = (const float*)d_in[1];
  const float* hp     = (const float*)d_in[2];
  const float* ra_w1  = (const float*)d_in[3];
  const float* ra_w2  = (const float*)d_in[4];
  const float* ra_b2  = (const float*)d_in[5];
  const float* dw_w   = (const float*)d_in[6];
  const float* dw_b   = (const float*)d_in[7];
  const float* pw_w   = (const float*)d_in[8];
  const float* pw_b   = (const float*)d_in[9];
  const float* fuse_w = (const float*)d_in[10];
  const float* fuse_b = (const float*)d_in[11];
  float* ws = (float*)d_ws;
  float* out = (float*)d_out;

  prep_kernel<<<17, 256, 0, stream>>>(ra_w1, ra_w2, ra_b2, pw_w, ws);
  attn_kernel<<<dim3(256, 256), 256, 0, stream>>>(reused, ws, out);
  apply_kernel<<<dim3(256, 8), 256, 0, stream>>>(out, lms, ws + WS_REFL);
  dw_kernel<<<16384, 256, 0, stream>>>(ws + WS_REFL, dw_w, dw_b, ws + WS_DWOUT);
  pw_kernel<<<dim3(256, 4), 256, 0, stream>>>(ws, pw_b, ws + WS_RES);
  fuse_kernel<<<dim3(64, 4, 4), 256, 0, stream>>>(ws, hp, fuse_w, fuse_b, out + ATTN_ELEMS);
}